// Round 1
// baseline (440.430 us; speedup 1.0000x reference)
//
#include <hip/hip_runtime.h>
#include <hip/hip_bf16.h>
#include <math.h>

#define NTOK 1600
#define CDIM 256
#define DK   64

// ---------------------------------------------------------------------------
// Kernel A: geometric relation table.  g depends only on (|dy|,|dx|) since the
// bbox (w,h)=(1,1) components are constant.  1600 entries instead of 2.56M.
// Weight reads are wave-uniform -> compiler emits scalar loads.
// ---------------------------------------------------------------------------
__global__ __launch_bounds__(256) void geo_table_kernel(
    const float* __restrict__ Wg1, const float* __restrict__ bg1,
    const float* __restrict__ Wg2, const float* __restrict__ bg2,
    const float* __restrict__ Wgr, const float* __restrict__ bgr,
    float* __restrict__ table)
{
    int idx = blockIdx.x * 256 + threadIdx.x;
    if (idx >= NTOK) return;
    int ady = idx / 40, adx = idx % 40;
    float g0 = logf((float)adx + 1e-8f);
    float g1 = logf((float)ady + 1e-8f);
    float gc = logf(1e-8f);        // w,h diffs are 0 -> log(1e-8)

    float e1[64];
    #pragma unroll
    for (int j = 0; j < 64; ++j) {
        float t = g0 * Wg1[0*64 + j] + g1 * Wg1[1*64 + j]
                + gc * (Wg1[2*64 + j] + Wg1[3*64 + j]) + bg1[j];
        e1[j] = fmaxf(t, 0.f);
    }
    float wg[16];
    #pragma unroll
    for (int r = 0; r < 16; ++r) wg[r] = bgr[r];
    for (int j = 0; j < 64; ++j) {
        float t = bg2[j];
        #pragma unroll
        for (int i = 0; i < 64; ++i) t += e1[i] * Wg2[i*64 + j];
        t = fmaxf(t, 0.f);
        #pragma unroll
        for (int r = 0; r < 16; ++r) wg[r] += t * Wgr[j*16 + r];
    }
    float s = 0.f;
    #pragma unroll
    for (int r = 0; r < 16; ++r) s += fmaxf(wg[r], 0.f);
    table[idx] = s * (1.f / 16.f);
}

// ---------------------------------------------------------------------------
// Kernel B: QKV projection GEMM.  feats[n][c] = x[b][c][n] (transpose done in
// the LDS tile).  grid = (ntile=25, jtile=6 {Q,K,V0..V3}, b=4).
// 64x64 output tile, 4x4 register micro-tile per thread.
// ---------------------------------------------------------------------------
__global__ __launch_bounds__(256) void qkv_gemm_kernel(
    const float* __restrict__ x,
    const float* __restrict__ Wq, const float* __restrict__ bq,
    const float* __restrict__ Wk, const float* __restrict__ bk,
    const float* __restrict__ Wv, const float* __restrict__ bv,
    float* __restrict__ Qw, float* __restrict__ Kw, float* __restrict__ Vw)
{
    const int N = NTOK, C = CDIM;
    int bx = blockIdx.x;          // n tile
    int jt = blockIdx.y;          // 0:Q 1:K 2..5:V columns
    int b  = blockIdx.z;

    const float* Wm; const float* bias; float* outp;
    int jb, stride, Jdim;
    if (jt == 0)      { Wm = Wq; bias = bq; jb = 0;           stride = 64;  Jdim = 64;  outp = Qw + (size_t)b*N*64;  }
    else if (jt == 1) { Wm = Wk; bias = bk; jb = 0;           stride = 64;  Jdim = 64;  outp = Kw + (size_t)b*N*64;  }
    else              { Wm = Wv; bias = bv; jb = (jt-2)*64;   stride = 256; Jdim = 256; outp = Vw + (size_t)b*N*256; }

    __shared__ __align__(16) float xs[64*68];
    __shared__ __align__(16) float wm[64*68];

    int t  = threadIdx.x;
    int tn = t & 15;              // n sub-tile
    int tj = t >> 4;              // j sub-tile
    int n0 = bx * 64;

    float acc[4][4] = {};

    for (int kc = 0; kc < 4; ++kc) {
        int k0 = kc * 64;
        #pragma unroll
        for (int p = 0; p < 16; ++p) {
            int idx = p*256 + t; int row = idx >> 6, col = idx & 63;
            xs[row*68 + col] = x[(size_t)b*C*N + (size_t)(k0+row)*N + n0 + col];
            wm[row*68 + col] = Wm[(size_t)(k0+row)*stride + jb + col];
        }
        __syncthreads();
        #pragma unroll
        for (int kk = 0; kk < 64; ++kk) {
            float4 xv = *(const float4*)(xs + kk*68 + tn*4);
            float4 wv = *(const float4*)(wm + kk*68 + tj*4);
            acc[0][0] += xv.x*wv.x; acc[0][1] += xv.x*wv.y; acc[0][2] += xv.x*wv.z; acc[0][3] += xv.x*wv.w;
            acc[1][0] += xv.y*wv.x; acc[1][1] += xv.y*wv.y; acc[1][2] += xv.y*wv.z; acc[1][3] += xv.y*wv.w;
            acc[2][0] += xv.z*wv.x; acc[2][1] += xv.z*wv.y; acc[2][2] += xv.z*wv.z; acc[2][3] += xv.z*wv.w;
            acc[3][0] += xv.w*wv.x; acc[3][1] += xv.w*wv.y; acc[3][2] += xv.w*wv.z; acc[3][3] += xv.w*wv.w;
        }
        __syncthreads();
    }
    #pragma unroll
    for (int ii = 0; ii < 4; ++ii) {
        int n = n0 + tn*4 + ii;
        #pragma unroll
        for (int jj = 0; jj < 4; ++jj) {
            int jl = tj*4 + jj;
            outp[(size_t)n*Jdim + jb + jl] = acc[ii][jj] + bias[jb + jl];
        }
    }
}

// ---------------------------------------------------------------------------
// Kernel C: fused attention.  One block = (b, 16 query rows).  Online softmax
// over 25 chunks of 64 keys; geo weight gathered from LDS table (multiplies
// the numerator only); PV = P[16][64] @ V[64][256] register-tiled with
// coalesced global V reads (V[b] is L2-resident).  Output written with an
// LDS transpose so stores along n are coalesced, residual x added.
// ---------------------------------------------------------------------------
__global__ __launch_bounds__(256) void attn_fused_kernel(
    const float* __restrict__ x,
    const float* __restrict__ gtab,
    const float* __restrict__ Qw, const float* __restrict__ Kw,
    const float* __restrict__ Vw, float* __restrict__ out)
{
    const int N = NTOK, C = CDIM;
    int b  = blockIdx.y;
    int n0 = blockIdx.x * 16;
    int t  = threadIdx.x;

    __shared__ __align__(16) float sh_un[64*68];   // K tile [64][68] / trans [256][17]
    __shared__ __align__(16) float sh_q[16*64];
    __shared__ __align__(16) float sh_p[64*20];    // P^T: [m][r], stride 20 for aligned float4
    __shared__ __align__(16) float sh_g[NTOK];
    __shared__ float sh_M[16], sh_Z[16], sh_F[16];

    // load Q tile (pre-scaled by 1/sqrt(dk)=0.125)
    #pragma unroll
    for (int p = 0; p < 4; ++p) {
        int idx = p*256 + t; int r = idx >> 6, i = idx & 63;
        sh_q[r*64 + i] = Qw[(size_t)b*N*DK + (size_t)(n0 + r)*DK + i] * 0.125f;
    }
    // load geo table
    #pragma unroll
    for (int p = 0; p < 7; ++p) {
        int idx = p*256 + t;
        if (idx < NTOK) sh_g[idx] = gtab[idx];
    }
    if (t < 16) { sh_M[t] = -INFINITY; sh_Z[t] = 0.f; }

    // score-phase ids: 16 lanes per row, 4 m's per lane
    int sr = t >> 4, lane = t & 15;
    int n_glob = n0 + sr;
    int yn = n_glob / 40, xn = n_glob % 40;
    // pv-phase ids: 4 row-groups x 64 column-threads
    int ri = t >> 6, ci = t & 63;

    float acc[4][4] = {};

    for (int cc = 0; cc < 25; ++cc) {
        int m0 = cc * 64;
        __syncthreads();
        // stage K chunk
        #pragma unroll
        for (int p = 0; p < 16; ++p) {
            int idx = p*256 + t; int m = idx >> 6, i = idx & 63;
            sh_un[m*68 + i] = Kw[(size_t)b*N*DK + (size_t)(m0 + m)*DK + i];
        }
        __syncthreads();

        // scores s[r][m] for my 4 m's
        float s[4] = {0.f, 0.f, 0.f, 0.f};
        #pragma unroll
        for (int i4 = 0; i4 < 16; ++i4) {
            float4 qv = *(const float4*)(sh_q + sr*64 + i4*4);
            #pragma unroll
            for (int mm = 0; mm < 4; ++mm) {
                float4 kv = *(const float4*)(sh_un + (lane + 16*mm)*68 + i4*4);
                s[mm] += qv.x*kv.x + qv.y*kv.y + qv.z*kv.z + qv.w*kv.w;
            }
        }
        // row max (online softmax)
        float lmax = fmaxf(fmaxf(s[0], s[1]), fmaxf(s[2], s[3]));
        #pragma unroll
        for (int off = 8; off >= 1; off >>= 1) lmax = fmaxf(lmax, __shfl_xor(lmax, off));
        float Mold = sh_M[sr];
        float Mnew = fmaxf(Mold, lmax);
        float f    = __expf(Mold - Mnew);      // exp(-inf)=0 on first chunk
        float e[4];
        float zloc = 0.f;
        #pragma unroll
        for (int mm = 0; mm < 4; ++mm) { e[mm] = __expf(s[mm] - Mnew); zloc += e[mm]; }
        #pragma unroll
        for (int off = 8; off >= 1; off >>= 1) zloc += __shfl_xor(zloc, off);
        // numerator gets the geo weight; denominator (softmax) does not
        #pragma unroll
        for (int mm = 0; mm < 4; ++mm) {
            int m_glob = m0 + lane + 16*mm;
            int ym = m_glob / 40, xm = m_glob % 40;
            int ady = ym - yn; ady = ady < 0 ? -ady : ady;
            int adx = xm - xn; adx = adx < 0 ? -adx : adx;
            sh_p[(lane + 16*mm)*20 + sr] = e[mm] * sh_g[ady*40 + adx];
        }
        if (lane == 0) {
            sh_Z[sr] = sh_Z[sr] * f + zloc;
            sh_M[sr] = Mnew;
            sh_F[sr] = f;
        }
        __syncthreads();

        // PV: acc[4r][4c] += P[16][64] @ V[64][256]
        float fac[4];
        #pragma unroll
        for (int rr = 0; rr < 4; ++rr) fac[rr] = sh_F[ri*4 + rr];
        #pragma unroll
        for (int rr = 0; rr < 4; ++rr)
            #pragma unroll
            for (int jj = 0; jj < 4; ++jj) acc[rr][jj] *= fac[rr];

        const float* vbase = Vw + (size_t)b*N*C + (size_t)m0*C + ci*4;
        #pragma unroll 2
        for (int m = 0; m < 64; ++m) {
            float4 pv = *(const float4*)(sh_p + m*20 + ri*4);
            float4 vv = *(const float4*)(vbase + (size_t)m*C);
            acc[0][0] += pv.x*vv.x; acc[0][1] += pv.x*vv.y; acc[0][2] += pv.x*vv.z; acc[0][3] += pv.x*vv.w;
            acc[1][0] += pv.y*vv.x; acc[1][1] += pv.y*vv.y; acc[1][2] += pv.y*vv.z; acc[1][3] += pv.y*vv.w;
            acc[2][0] += pv.z*vv.x; acc[2][1] += pv.z*vv.y; acc[2][2] += pv.z*vv.z; acc[2][3] += pv.z*vv.w;
            acc[3][0] += pv.w*vv.x; acc[3][1] += pv.w*vv.y; acc[3][2] += pv.w*vv.z; acc[3][3] += pv.w*vv.w;
        }
    }
    __syncthreads();

    // epilogue: normalize, transpose through LDS, coalesced store with residual
    float invZ[4];
    #pragma unroll
    for (int rr = 0; rr < 4; ++rr) invZ[rr] = 1.f / sh_Z[ri*4 + rr];
    #pragma unroll
    for (int rr = 0; rr < 4; ++rr)
        #pragma unroll
        for (int jj = 0; jj < 4; ++jj)
            sh_un[(ci*4 + jj)*17 + ri*4 + rr] = acc[rr][jj] * invZ[rr];
    __syncthreads();
    #pragma unroll
    for (int p = 0; p < 16; ++p) {
        int c2 = p*16 + (t >> 4), r2 = t & 15;
        size_t gi = (size_t)b*C*N + (size_t)c2*N + n0 + r2;
        out[gi] = x[gi] + sh_un[c2*17 + r2];
    }
}

// ---------------------------------------------------------------------------
extern "C" void kernel_launch(void* const* d_in, const int* in_sizes, int n_in,
                              void* d_out, int out_size, void* d_ws, size_t ws_size,
                              hipStream_t stream)
{
    const float* x   = (const float*)d_in[0];
    const float* Wq  = (const float*)d_in[1];
    const float* bq  = (const float*)d_in[2];
    const float* Wk  = (const float*)d_in[3];
    const float* bk  = (const float*)d_in[4];
    const float* Wv  = (const float*)d_in[5];
    const float* bv  = (const float*)d_in[6];
    const float* Wg1 = (const float*)d_in[7];
    const float* bg1 = (const float*)d_in[8];
    const float* Wg2 = (const float*)d_in[9];
    const float* bg2 = (const float*)d_in[10];
    const float* Wgr = (const float*)d_in[11];
    const float* bgr = (const float*)d_in[12];

    float* ws    = (float*)d_ws;
    float* table = ws;                        // 1600 floats
    float* Qw    = ws + 2048;                 // 4*1600*64
    float* Kw    = Qw + 4*NTOK*DK;            // 4*1600*64
    float* Vw    = Kw + 4*NTOK*DK;            // 4*1600*256

    geo_table_kernel<<<dim3(7), dim3(256), 0, stream>>>(Wg1, bg1, Wg2, bg2, Wgr, bgr, table);
    qkv_gemm_kernel<<<dim3(25, 6, 4), dim3(256), 0, stream>>>(x, Wq, bq, Wk, bk, Wv, bv, Qw, Kw, Vw);
    attn_fused_kernel<<<dim3(100, 4), dim3(256), 0, stream>>>(x, table, Qw, Kw, Vw, (float*)d_out);
}

// Round 3
// 209.843 us; speedup vs baseline: 2.0989x; 2.0989x over previous
//
#include <hip/hip_runtime.h>
#include <hip/hip_bf16.h>
#include <math.h>

#define NTOK 1600
#define CDIM 256
#define DK   64

typedef __attribute__((ext_vector_type(8))) short bf16x8;
typedef __attribute__((ext_vector_type(4))) float f32x4;

__device__ inline unsigned short f2bf(float v) {
    unsigned int u = __float_as_uint(v);
    unsigned int r = (u + 0x7fffu + ((u >> 16) & 1u)) >> 16;
    return (unsigned short)r;
}

// ---------------------------------------------------------------------------
// Kernel A: geometric relation table (1600 entries, keyed by (|dy|,|dx|)).
// ---------------------------------------------------------------------------
__global__ __launch_bounds__(256) void geo_table_kernel(
    const float* __restrict__ Wg1, const float* __restrict__ bg1,
    const float* __restrict__ Wg2, const float* __restrict__ bg2,
    const float* __restrict__ Wgr, const float* __restrict__ bgr,
    float* __restrict__ table)
{
    int idx = blockIdx.x * 256 + threadIdx.x;
    if (idx >= NTOK) return;
    int ady = idx / 40, adx = idx % 40;
    float g0 = logf((float)adx + 1e-8f);
    float g1 = logf((float)ady + 1e-8f);
    float gc = logf(1e-8f);

    float e1[64];
    #pragma unroll
    for (int j = 0; j < 64; ++j) {
        float t = g0 * Wg1[0*64 + j] + g1 * Wg1[1*64 + j]
                + gc * (Wg1[2*64 + j] + Wg1[3*64 + j]) + bg1[j];
        e1[j] = fmaxf(t, 0.f);
    }
    float wg[16];
    #pragma unroll
    for (int r = 0; r < 16; ++r) wg[r] = bgr[r];
    for (int j = 0; j < 64; ++j) {
        float t = bg2[j];
        #pragma unroll
        for (int i = 0; i < 64; ++i) t += e1[i] * Wg2[i*64 + j];
        t = fmaxf(t, 0.f);
        #pragma unroll
        for (int r = 0; r < 16; ++r) wg[r] += t * Wgr[j*16 + r];
    }
    float s = 0.f;
    #pragma unroll
    for (int r = 0; r < 16; ++r) s += fmaxf(wg[r], 0.f);
    table[idx] = s * (1.f / 16.f);
}

// ---------------------------------------------------------------------------
// Kernel B: QKV projection (f32 compute, bf16 outputs).
//   Qb[b][n][64]  bf16, pre-scaled by 1/sqrt(64)
//   Kb[b][n][64]  bf16
//   Vt[b][c][n]   bf16 (transposed so PV B-fragments are contiguous)
// grid = (25 n-tiles, 6 j-tiles {Q,K,V0..3}, 4 b)
// ---------------------------------------------------------------------------
__global__ __launch_bounds__(256) void qkv_kernel(
    const float* __restrict__ x,
    const float* __restrict__ Wq, const float* __restrict__ bq,
    const float* __restrict__ Wk, const float* __restrict__ bk,
    const float* __restrict__ Wv, const float* __restrict__ bv,
    unsigned short* __restrict__ Qb, unsigned short* __restrict__ Kb,
    unsigned short* __restrict__ Vt)
{
    const int N = NTOK, C = CDIM;
    int bx = blockIdx.x;
    int jt = blockIdx.y;
    int b  = blockIdx.z;

    const float* Wm; const float* bias;
    int jb, stride;
    if (jt == 0)      { Wm = Wq; bias = bq; jb = 0;         stride = 64;  }
    else if (jt == 1) { Wm = Wk; bias = bk; jb = 0;         stride = 64;  }
    else              { Wm = Wv; bias = bv; jb = (jt-2)*64; stride = 256; }

    __shared__ __align__(16) float xs[64*68];
    __shared__ __align__(16) float wm[64*68];

    int t  = threadIdx.x;
    int tn = t & 15;
    int tj = t >> 4;
    int n0 = bx * 64;

    float acc[4][4] = {};

    for (int kc = 0; kc < 4; ++kc) {
        int k0 = kc * 64;
        #pragma unroll
        for (int p = 0; p < 4; ++p) {
            int idx4 = p*256 + t;
            int row = idx4 >> 4, col4 = (idx4 & 15) * 4;
            *(float4*)&xs[row*68 + col4] =
                *(const float4*)&x[(size_t)(b*C + k0 + row)*N + n0 + col4];
            *(float4*)&wm[row*68 + col4] =
                *(const float4*)&Wm[(size_t)(k0 + row)*stride + jb + col4];
        }
        __syncthreads();
        #pragma unroll
        for (int kk = 0; kk < 64; ++kk) {
            float4 xv = *(const float4*)(xs + kk*68 + tn*4);
            float4 wv = *(const float4*)(wm + kk*68 + tj*4);
            acc[0][0] += xv.x*wv.x; acc[0][1] += xv.x*wv.y; acc[0][2] += xv.x*wv.z; acc[0][3] += xv.x*wv.w;
            acc[1][0] += xv.y*wv.x; acc[1][1] += xv.y*wv.y; acc[1][2] += xv.y*wv.z; acc[1][3] += xv.y*wv.w;
            acc[2][0] += xv.z*wv.x; acc[2][1] += xv.z*wv.y; acc[2][2] += xv.z*wv.z; acc[2][3] += xv.z*wv.w;
            acc[3][0] += xv.w*wv.x; acc[3][1] += xv.w*wv.y; acc[3][2] += xv.w*wv.z; acc[3][3] += xv.w*wv.w;
        }
        __syncthreads();
    }

    if (jt <= 1) {
        unsigned short* outb = (jt == 0 ? Qb : Kb) + (size_t)b*N*DK;
        float scale = (jt == 0) ? 0.125f : 1.0f;
        #pragma unroll
        for (int ii = 0; ii < 4; ++ii) {
            int n = n0 + tn*4 + ii;
            __align__(8) unsigned short u[4];
            #pragma unroll
            for (int jj = 0; jj < 4; ++jj)
                u[jj] = f2bf((acc[ii][jj] + bias[tj*4 + jj]) * scale);
            *(uint2*)&outb[(size_t)n*DK + tj*4] = *(const uint2*)u;
        }
    } else {
        // stage to LDS, write transposed bf16 rows of Vt
        #pragma unroll
        for (int ii = 0; ii < 4; ++ii)
            #pragma unroll
            for (int jj = 0; jj < 4; ++jj)
                xs[(tn*4 + ii)*68 + tj*4 + jj] = acc[ii][jj] + bias[jb + tj*4 + jj];
        __syncthreads();
        int jl = t >> 2, nb = (t & 3) * 16;
        __align__(16) unsigned short u[16];
        #pragma unroll
        for (int i = 0; i < 16; ++i)
            u[i] = f2bf(xs[(nb + i)*68 + jl]);
        unsigned short* vrow = Vt + ((size_t)b*C + jb + jl)*N + n0 + nb;
        ((uint4*)vrow)[0] = ((const uint4*)u)[0];
        ((uint4*)vrow)[1] = ((const uint4*)u)[1];
    }
}

// ---------------------------------------------------------------------------
// Kernel C: MFMA attention, single pass, no online softmax.
//   acc[n][c] = sum_m exp(s[n][m]) * g[n][m] * V[m][c];  Z[n] = sum_m exp(s)
//   out = x + acc / Z
// Block = 16 query rows, 256 threads = 4 waves.
//   S phase: wave w computes S[16][16] for key slice m0+16w (2 MFMA),
//            e=exp(s), z+=e, P = e*g -> bf16 LDS tile (double-buffered)
//   PV phase: wave w owns c-slice [64w,64w+64): 8 MFMA vs Vt, A-frags from P.
// grid = (100 n-tiles, 4 b)
// ---------------------------------------------------------------------------
__global__ __launch_bounds__(256) void attn_mfma_kernel(
    const float* __restrict__ x, const float* __restrict__ gtab,
    const unsigned short* __restrict__ Qb, const unsigned short* __restrict__ Kb,
    const unsigned short* __restrict__ Vt, float* __restrict__ out)
{
    const int N = NTOK, C = CDIM;
    int b = blockIdx.y, n0 = blockIdx.x * 16;
    int t = threadIdx.x;
    int w = t >> 6, l = t & 63;
    int l15 = l & 15, l4 = l >> 4;

    __shared__ unsigned short Pl[2][16*72];          // P tile, pad 72
    __shared__ float sh_g[NTOK];
    __shared__ float shZ[4][16];
    __shared__ __align__(16) float outs[256*17];

    #pragma unroll
    for (int p = 0; p < 7; ++p) { int i = p*256 + t; if (i < NTOK) sh_g[i] = gtab[i]; }

    // Q A-fragments (row = l&15, k0 = 8*(l>>4)), reused for all chunks
    const unsigned short* qrow = &Qb[((size_t)b*N + n0 + l15)*DK + l4*8];
    bf16x8 qa0 = *(const bf16x8*)qrow;
    bf16x8 qa1 = *(const bf16x8*)(qrow + 32);

    f32x4 acc[4];
    #pragma unroll
    for (int i = 0; i < 4; ++i) acc[i] = (f32x4){0.f, 0.f, 0.f, 0.f};
    float z[4] = {0.f, 0.f, 0.f, 0.f};

    int yn[4], xn[4];
    #pragma unroll
    for (int r = 0; r < 4; ++r) {
        int n = n0 + l4*4 + r;
        yn[r] = n / 40; xn[r] = n - 40*yn[r];
    }
    int mcol = w*16 + l15;     // this lane's key column within the 64-chunk

    __syncthreads();

    for (int cc = 0; cc < 25; ++cc) {
        int m0 = cc * 64;
        // ---- S phase: 16 rows x 16 keys for this wave ----
        const unsigned short* kbase = &Kb[((size_t)b*N + m0 + mcol)*DK + l4*8];
        bf16x8 kb0 = *(const bf16x8*)kbase;
        bf16x8 kb1 = *(const bf16x8*)(kbase + 32);
        f32x4 s4 = (f32x4){0.f, 0.f, 0.f, 0.f};
        s4 = __builtin_amdgcn_mfma_f32_16x16x32_bf16(qa0, kb0, s4, 0, 0, 0);
        s4 = __builtin_amdgcn_mfma_f32_16x16x32_bf16(qa1, kb1, s4, 0, 0, 0);

        int mg = m0 + mcol;
        int ym = mg / 40, xm = mg - 40*ym;
        unsigned short* prow = &Pl[cc & 1][0];
        #pragma unroll
        for (int r = 0; r < 4; ++r) {
            float e = __expf(s4[r]);
            z[r] += e;
            int ady = ym - yn[r]; ady = ady < 0 ? -ady : ady;
            int adx = xm - xn[r]; adx = adx < 0 ? -adx : adx;
            float p = e * sh_g[ady*40 + adx];
            prow[(l4*4 + r)*72 + mcol] = f2bf(p);
        }
        __syncthreads();

        // ---- PV phase: c-slice [64w, 64w+64) ----
        const unsigned short* pb = &Pl[cc & 1][l15*72 + l4*8];
        bf16x8 pa0 = *(const bf16x8*)pb;
        bf16x8 pa1 = *(const bf16x8*)(pb + 32);
        #pragma unroll
        for (int t4 = 0; t4 < 4; ++t4) {
            int c0 = w*64 + t4*16 + l15;
            const unsigned short* vb = &Vt[((size_t)b*C + c0)*N + m0 + l4*8];
            bf16x8 v0 = *(const bf16x8*)vb;
            bf16x8 v1 = *(const bf16x8*)(vb + 32);
            acc[t4] = __builtin_amdgcn_mfma_f32_16x16x32_bf16(pa0, v0, acc[t4], 0, 0, 0);
            acc[t4] = __builtin_amdgcn_mfma_f32_16x16x32_bf16(pa1, v1, acc[t4], 0, 0, 0);
        }
        // no trailing barrier: P is double-buffered
    }

    // ---- Z: reduce over the 16 key-columns, then across the 4 waves ----
    #pragma unroll
    for (int r = 0; r < 4; ++r) {
        float v = z[r];
        v += __shfl_xor(v, 1); v += __shfl_xor(v, 2);
        v += __shfl_xor(v, 4); v += __shfl_xor(v, 8);
        z[r] = v;
    }
    if (l15 == 0) {
        #pragma unroll
        for (int r = 0; r < 4; ++r) shZ[w][l4*4 + r] = z[r];
    }
    __syncthreads();

    float invz[4];
    #pragma unroll
    for (int r = 0; r < 4; ++r) {
        int row = l4*4 + r;
        float s = shZ[0][row] + shZ[1][row] + shZ[2][row] + shZ[3][row];
        invz[r] = 1.f / s;
    }
    #pragma unroll
    for (int t4 = 0; t4 < 4; ++t4)
        #pragma unroll
        for (int r = 0; r < 4; ++r)
            outs[(w*64 + t4*16 + l15)*17 + l4*4 + r] = acc[t4][r] * invz[r];
    __syncthreads();

    #pragma unroll
    for (int p = 0; p < 16; ++p) {
        int c2 = p*16 + (t >> 4), r2 = t & 15;
        size_t gi = (size_t)b*C*N + (size_t)c2*N + n0 + r2;
        out[gi] = x[gi] + outs[c2*17 + r2];
    }
}

// ---------------------------------------------------------------------------
extern "C" void kernel_launch(void* const* d_in, const int* in_sizes, int n_in,
                              void* d_out, int out_size, void* d_ws, size_t ws_size,
                              hipStream_t stream)
{
    const float* x   = (const float*)d_in[0];
    const float* Wq  = (const float*)d_in[1];
    const float* bq  = (const float*)d_in[2];
    const float* Wk  = (const float*)d_in[3];
    const float* bk  = (const float*)d_in[4];
    const float* Wv  = (const float*)d_in[5];
    const float* bv  = (const float*)d_in[6];
    const float* Wg1 = (const float*)d_in[7];
    const float* bg1 = (const float*)d_in[8];
    const float* Wg2 = (const float*)d_in[9];
    const float* bg2 = (const float*)d_in[10];
    const float* Wgr = (const float*)d_in[11];
    const float* bgr = (const float*)d_in[12];

    char* ws = (char*)d_ws;
    float* table          = (float*)ws;                         // 6400 B
    unsigned short* Qb    = (unsigned short*)(ws + 8192);       // 819200 B
    unsigned short* Kb    = (unsigned short*)(ws + 8192 + 819200);
    unsigned short* Vt    = (unsigned short*)(ws + 8192 + 2*819200);  // 3276800 B

    geo_table_kernel<<<dim3(7), dim3(256), 0, stream>>>(Wg1, bg1, Wg2, bg2, Wgr, bgr, table);
    qkv_kernel<<<dim3(25, 6, 4), dim3(256), 0, stream>>>(x, Wq, bq, Wk, bk, Wv, bv, Qb, Kb, Vt);
    attn_mfma_kernel<<<dim3(100, 4), dim3(256), 0, stream>>>(x, table, Qb, Kb, Vt, (float*)d_out);
}

// Round 4
// 204.548 us; speedup vs baseline: 2.1532x; 1.0259x over previous
//
#include <hip/hip_runtime.h>
#include <hip/hip_bf16.h>
#include <math.h>

#define NTOK 1600
#define CDIM 256
#define DK   64

typedef __attribute__((ext_vector_type(8))) short bf16x8;
typedef __attribute__((ext_vector_type(4))) float f32x4;

__device__ inline unsigned short f2bf(float v) {
    unsigned int u = __float_as_uint(v);
    unsigned int r = (u + 0x7fffu + ((u >> 16) & 1u)) >> 16;
    return (unsigned short)r;
}

// ---------------------------------------------------------------------------
// Kernel A: geometric relation table, wave-per-idx (1600 waves, 400 blocks).
// e1 = relu(W1^T g); e2 = relu(W2^T e1); wg = relu(Wgr^T e2); mean -> table.
// ---------------------------------------------------------------------------
__global__ __launch_bounds__(256) void geo_table_kernel(
    const float* __restrict__ W1, const float* __restrict__ b1,
    const float* __restrict__ W2, const float* __restrict__ b2,
    const float* __restrict__ Wgr, const float* __restrict__ bgr,
    float* __restrict__ table)
{
    __shared__ float e1s[4][64];
    __shared__ float e2s[4][64];
    int t = threadIdx.x;
    int w = t >> 6, j = t & 63;
    int idx = blockIdx.x * 4 + w;            // grid 400 * 4 waves = 1600 exact
    int ady = idx / 40, adx = idx % 40;
    float g0 = logf((float)adx + 1e-8f);
    float g1 = logf((float)ady + 1e-8f);
    float gc = logf(1e-8f);

    float e1 = fmaxf(g0*W1[j] + g1*W1[64+j] + gc*(W1[128+j]+W1[192+j]) + b1[j], 0.f);
    e1s[w][j] = e1;
    __syncthreads();

    float e2 = b2[j];
    #pragma unroll 8
    for (int i = 0; i < 64; ++i) e2 += e1s[w][i] * W2[i*64 + j];
    e2 = fmaxf(e2, 0.f);
    e2s[w][j] = e2;
    __syncthreads();

    int r = j & 15, q = j >> 4;
    float v = (q == 0) ? bgr[r] : 0.f;
    #pragma unroll
    for (int i = 0; i < 16; ++i) v += e2s[w][q*16 + i] * Wgr[(q*16 + i)*16 + r];
    v += __shfl_xor(v, 16); v += __shfl_xor(v, 32);   // sum quarters -> wg[r]
    v = fmaxf(v, 0.f);                                 // relu
    v += __shfl_xor(v, 1); v += __shfl_xor(v, 2);      // sum over r
    v += __shfl_xor(v, 4); v += __shfl_xor(v, 8);
    if (j == 0) table[idx] = v * (1.f / 16.f);
}

// ---------------------------------------------------------------------------
// Kernel B: QKV projection via bf16 MFMA.
//   A = feats (x transposed in LDS), B = W column tile (transposed in LDS).
//   Qb[b][n][64] (x0.125), Kb[b][n][64], Vt[b][c][n].
// grid (25 ntiles, 6 jt, 4 b), 256 thr = 4 waves; wave w owns n-rows w*16..+15.
// ---------------------------------------------------------------------------
__global__ __launch_bounds__(256) void qkv_kernel(
    const float* __restrict__ x,
    const float* __restrict__ Wq, const float* __restrict__ bq,
    const float* __restrict__ Wk, const float* __restrict__ bk,
    const float* __restrict__ Wv, const float* __restrict__ bv,
    unsigned short* __restrict__ Qb, unsigned short* __restrict__ Kb,
    unsigned short* __restrict__ Vt)
{
    const int N = NTOK;
    int bx = blockIdx.x, jt = blockIdx.y, b = blockIdx.z;
    const float* Wm; const float* bias; int jb, stride;
    if (jt == 0)      { Wm = Wq; bias = bq; jb = 0;         stride = 64;  }
    else if (jt == 1) { Wm = Wk; bias = bk; jb = 0;         stride = 64;  }
    else              { Wm = Wv; bias = bv; jb = (jt-2)*64; stride = 256; }

    __shared__ __align__(16) unsigned short As[64*72];   // [n][k] pad 72
    __shared__ __align__(16) unsigned short Bs[64*72];   // [j][k] pad 72

    int t = threadIdx.x;
    int w = t >> 6, l = t & 63;
    int l15 = l & 15, l4 = l >> 4;
    int n0 = bx * 64;

    f32x4 acc[4];
    #pragma unroll
    for (int i = 0; i < 4; ++i) acc[i] = (f32x4){0.f,0.f,0.f,0.f};

    for (int kc = 0; kc < 4; ++kc) {
        int k0 = kc * 64;
        __syncthreads();    // previous iter's reads done before overwrite
        #pragma unroll
        for (int p = 0; p < 4; ++p) {
            int k = p*16 + (t >> 4);
            int n4 = (t & 15) * 4;
            float4 xv = *(const float4*)&x[((size_t)(b*CDIM) + k0 + k)*N + n0 + n4];
            As[(n4+0)*72 + k] = f2bf(xv.x); As[(n4+1)*72 + k] = f2bf(xv.y);
            As[(n4+2)*72 + k] = f2bf(xv.z); As[(n4+3)*72 + k] = f2bf(xv.w);
            float4 wv = *(const float4*)&Wm[(size_t)(k0 + k)*stride + jb + n4];
            Bs[(n4+0)*72 + k] = f2bf(wv.x); Bs[(n4+1)*72 + k] = f2bf(wv.y);
            Bs[(n4+2)*72 + k] = f2bf(wv.z); Bs[(n4+3)*72 + k] = f2bf(wv.w);
        }
        __syncthreads();
        #pragma unroll
        for (int ks = 0; ks < 2; ++ks) {
            bf16x8 a = *(const bf16x8*)&As[(w*16 + l15)*72 + ks*32 + l4*8];
            #pragma unroll
            for (int jt4 = 0; jt4 < 4; ++jt4) {
                bf16x8 bf = *(const bf16x8*)&Bs[(jt4*16 + l15)*72 + ks*32 + l4*8];
                acc[jt4] = __builtin_amdgcn_mfma_f32_16x16x32_bf16(a, bf, acc[jt4], 0, 0, 0);
            }
        }
    }
    // D layout: col j = l15 (within j-tile), row n-local = l4*4 + r

    if (jt <= 1) {
        unsigned short* outb = (jt == 0 ? Qb : Kb) + (size_t)b*N*DK;
        float scale = (jt == 0) ? 0.125f : 1.0f;
        #pragma unroll
        for (int jt4 = 0; jt4 < 4; ++jt4) {
            int j = jt4*16 + l15;
            float bb = bias[j];
            #pragma unroll
            for (int r = 0; r < 4; ++r) {
                int n = n0 + w*16 + l4*4 + r;
                outb[(size_t)n*DK + j] = f2bf((acc[jt4][r] + bb) * scale);
            }
        }
    } else {
        __syncthreads();   // all MFMA reads of As/Bs done; reuse as transpose buf
        // per-wave region [64 c][20 nl]
        unsigned short* sv = (w < 2 ? As : Bs) + (w & 1) * (64*20);
        #pragma unroll
        for (int jt4 = 0; jt4 < 4; ++jt4) {
            int j = jt4*16 + l15;
            float bb = bias[jb + j];
            #pragma unroll
            for (int r = 0; r < 4; ++r)
                sv[j*20 + l4*4 + r] = f2bf(acc[jt4][r] + bb);
        }
        __syncthreads();
        // lane l -> c = l: read 16 nl, two 16B stores
        int c = l;
        uint2 lo0 = *(const uint2*)&sv[c*20 + 0];
        uint2 lo1 = *(const uint2*)&sv[c*20 + 4];
        uint2 hi0 = *(const uint2*)&sv[c*20 + 8];
        uint2 hi1 = *(const uint2*)&sv[c*20 + 12];
        unsigned short* vrow = Vt + ((size_t)b*CDIM + jb + c)*N + n0 + w*16;
        *(uint4*)(vrow)     = make_uint4(lo0.x, lo0.y, lo1.x, lo1.y);
        *(uint4*)(vrow + 8) = make_uint4(hi0.x, hi0.y, hi1.x, hi1.y);
    }
}

// ---------------------------------------------------------------------------
// Kernel C: MFMA attention, wave-independent key chunks (NO main-loop barriers).
// Wave w processes chunks cc = w, w+4, ...: S (8 MFMA) -> exp*geo -> private
// LDS P tile -> PV (32 MFMA) into private acc[16]. Combine via ds_add at end.
// grid (100 ntiles, 4 b), 256 thr.
// ---------------------------------------------------------------------------
__global__ __launch_bounds__(256) void attn_kernel(
    const float* __restrict__ x, const float* __restrict__ gtab,
    const unsigned short* __restrict__ Qb, const unsigned short* __restrict__ Kb,
    const unsigned short* __restrict__ Vt, float* __restrict__ out)
{
    const int N = NTOK, C = CDIM;
    int b = blockIdx.y, n0 = blockIdx.x * 16;
    int t = threadIdx.x;
    int w = t >> 6, l = t & 63;
    int l15 = l & 15, l4 = l >> 4;

    __shared__ __align__(16) unsigned short Pl[4][16*72];  // per-wave P tiles
    __shared__ float sh_g[NTOK];
    __shared__ float outs[16][260];
    __shared__ float zs[16];

    for (int p = t; p < NTOK; p += 256) sh_g[p] = gtab[p];
    for (int p = t; p < 16*260; p += 256) ((float*)outs)[p] = 0.f;
    if (t < 16) zs[t] = 0.f;

    const unsigned short* qrow = &Qb[((size_t)b*N + n0 + l15)*DK + l4*8];
    bf16x8 qa0 = *(const bf16x8*)qrow;
    bf16x8 qa1 = *(const bf16x8*)(qrow + 32);

    f32x4 acc[16];
    #pragma unroll
    for (int i = 0; i < 16; ++i) acc[i] = (f32x4){0.f,0.f,0.f,0.f};
    float z[4] = {0.f, 0.f, 0.f, 0.f};

    int yn[4], xn[4];
    #pragma unroll
    for (int r = 0; r < 4; ++r) {
        int n = n0 + l4*4 + r;
        yn[r] = n / 40; xn[r] = n - 40*yn[r];
    }

    __syncthreads();                       // sh_g/outs/zs ready

    unsigned short* Pw = &Pl[w][0];

    for (int cc = w; cc < 25; cc += 4) {
        int m0 = cc * 64;
        // ---- S phase: 4 key sub-tiles of 16 ----
        #pragma unroll
        for (int tt = 0; tt < 4; ++tt) {
            int mg = m0 + tt*16 + l15;
            const unsigned short* kbase = &Kb[((size_t)b*N + mg)*DK + l4*8];
            bf16x8 kb0 = *(const bf16x8*)kbase;
            bf16x8 kb1 = *(const bf16x8*)(kbase + 32);
            f32x4 s4 = (f32x4){0.f,0.f,0.f,0.f};
            s4 = __builtin_amdgcn_mfma_f32_16x16x32_bf16(qa0, kb0, s4, 0, 0, 0);
            s4 = __builtin_amdgcn_mfma_f32_16x16x32_bf16(qa1, kb1, s4, 0, 0, 0);
            int ym = mg / 40, xm = mg - 40*ym;
            #pragma unroll
            for (int r = 0; r < 4; ++r) {
                float e = __expf(s4[r]);
                z[r] += e;
                int ady = ym - yn[r]; ady = ady < 0 ? -ady : ady;
                int adx = xm - xn[r]; adx = adx < 0 ? -adx : adx;
                Pw[(l4*4 + r)*72 + tt*16 + l15] = f2bf(e * sh_g[ady*40 + adx]);
            }
        }
        // ---- PV phase (same wave, compiler orders LDS via lgkmcnt) ----
        bf16x8 pa0 = *(const bf16x8*)&Pw[l15*72 + l4*8];
        bf16x8 pa1 = *(const bf16x8*)&Pw[l15*72 + 32 + l4*8];
        #pragma unroll
        for (int ct = 0; ct < 16; ++ct) {
            const unsigned short* vb = &Vt[((size_t)b*C + ct*16 + l15)*N + m0 + l4*8];
            bf16x8 v0 = *(const bf16x8*)vb;
            bf16x8 v1 = *(const bf16x8*)(vb + 32);
            acc[ct] = __builtin_amdgcn_mfma_f32_16x16x32_bf16(pa0, v0, acc[ct], 0, 0, 0);
            acc[ct] = __builtin_amdgcn_mfma_f32_16x16x32_bf16(pa1, v1, acc[ct], 0, 0, 0);
        }
    }

    // ---- combine partials across waves ----
    #pragma unroll
    for (int r = 0; r < 4; ++r) {
        float v = z[r];
        v += __shfl_xor(v, 1); v += __shfl_xor(v, 2);
        v += __shfl_xor(v, 4); v += __shfl_xor(v, 8);
        if (l15 == 0) atomicAdd(&zs[l4*4 + r], v);
    }
    #pragma unroll
    for (int ct = 0; ct < 16; ++ct)
        #pragma unroll
        for (int r = 0; r < 4; ++r)
            atomicAdd(&outs[l4*4 + r][ct*16 + l15], acc[ct][r]);
    __syncthreads();

    // ---- epilogue: normalize + residual, coalesced along n ----
    int r2 = t & 15;
    float invz = 1.f / zs[r2];
    #pragma unroll
    for (int p = 0; p < 16; ++p) {
        int c2 = p*16 + (t >> 4);
        size_t gi = ((size_t)b*C + c2)*N + n0 + r2;
        out[gi] = x[gi] + outs[r2][c2] * invz;
    }
}

// ---------------------------------------------------------------------------
extern "C" void kernel_launch(void* const* d_in, const int* in_sizes, int n_in,
                              void* d_out, int out_size, void* d_ws, size_t ws_size,
                              hipStream_t stream)
{
    const float* x   = (const float*)d_in[0];
    const float* Wq  = (const float*)d_in[1];
    const float* bq  = (const float*)d_in[2];
    const float* Wk  = (const float*)d_in[3];
    const float* bk  = (const float*)d_in[4];
    const float* Wv  = (const float*)d_in[5];
    const float* bv  = (const float*)d_in[6];
    const float* Wg1 = (const float*)d_in[7];
    const float* bg1 = (const float*)d_in[8];
    const float* Wg2 = (const float*)d_in[9];
    const float* bg2 = (const float*)d_in[10];
    const float* Wgr = (const float*)d_in[11];
    const float* bgr = (const float*)d_in[12];

    char* ws = (char*)d_ws;
    float* table       = (float*)ws;                              // 6400 B
    unsigned short* Qb = (unsigned short*)(ws + 8192);            // 819200 B
    unsigned short* Kb = (unsigned short*)(ws + 8192 + 819200);
    unsigned short* Vt = (unsigned short*)(ws + 8192 + 2*819200); // 3276800 B

    geo_table_kernel<<<dim3(400), dim3(256), 0, stream>>>(Wg1, bg1, Wg2, bg2, Wgr, bgr, table);
    qkv_kernel<<<dim3(25, 6, 4), dim3(256), 0, stream>>>(x, Wq, bq, Wk, bk, Wv, bv, Qb, Kb, Vt);
    attn_kernel<<<dim3(100, 4), dim3(256), 0, stream>>>(x, table, Qb, Kb, Vt, (float*)d_out);
}